// Round 3
// baseline (104.533 us; speedup 1.0000x reference)
//
#include <hip/hip_runtime.h>
#include <math.h>

#define IMH 512
#define IMW 512
#define T   32      // output tile
#define GS  40      // gray tile rows/cols (T+8)

// LDS pool layout (floats), all offsets/strides multiples of 4 (16B aligned).
#define LG  44
#define OG  0       // sG: 40 x 44  [0,1760)        col j <-> raw bx0-4+j
#define LH  40
#define OH  1760    // sH: 40 x 40  [1760,3360)     col j <-> clamped bx0-2+j (36 used)
#define LB  40
#define OB  3360    // sB: 36 x 40  [3360,4800)     col t <-> clamped bx0-6+t (t=4..39 valid)
#define LM  40
#define OM  4800    // sM: 34 x 40  [4800,6160)     col s <-> bx0-4+s (s=3..36 used)
#define LX  32
#define OGX 0       // sGX: 32 x 32 [0,1024)    (aliases sG - dead after P2)
#define OGY 1024    // sGY: 32 x 32 [1024,2048) (aliases sG/sH head - dead after P3)
#define NPOOL 6160  // 24640 B

__device__ __forceinline__ int reflect_i(int v, int n) {
    if (v < 0) v = -v;
    if (v >= n) v = 2 * n - 2 - v;
    return v;
}
__device__ __forceinline__ int clamp_i(int v, int n) {
    return v < 0 ? 0 : (v >= n ? n - 1 : v);
}

__global__ __launch_bounds__(256)
void canny_mag_kernel(const float* __restrict__ data, float* __restrict__ out) {
    __shared__ __align__(16) float sP[NPOOL];
    const int bx0 = blockIdx.x * T;
    const int by0 = blockIdx.y * T;
    const int b   = blockIdx.z;
    const int tid = threadIdx.x;
    const bool xin = (bx0 >= 4) && (bx0 + T + 4 <= IMW);   // no x-reflect needed
    const bool bin = (bx0 >= 1) && (bx0 + T + 1 <= IMW) &&
                     (by0 >= 1) && (by0 + T + 1 <= IMH);   // no NMS zero-border

    const float w0 = 0.05448868f, w1 = 0.24420134f, w2 = 0.40261995f;
    const size_t plane = (size_t)IMH * IMW;
    const float* p0 = data + (size_t)b * 3 * plane;
    const float* p1 = p0 + plane;
    const float* p2 = p1 + plane;

    // ---- Phase 1: gray = 0.1495*R + 0.2935*G + 0.057*B + 0.5 ----
    if (xin) {
        for (int idx = tid; idx < GS * 10; idx += 256) {
            int r = idx / 10, c4 = idx - r * 10;
            int ry = reflect_i(by0 - 4 + r, IMH);
            int off = ry * IMW + (bx0 - 4) + c4 * 4;
            const float4 a = *(const float4*)(p0 + off);
            const float4 g = *(const float4*)(p1 + off);
            const float4 c = *(const float4*)(p2 + off);
            float4 o;
            o.x = 0.1495f * a.x + 0.2935f * g.x + 0.057f * c.x + 0.5f;
            o.y = 0.1495f * a.y + 0.2935f * g.y + 0.057f * c.y + 0.5f;
            o.z = 0.1495f * a.z + 0.2935f * g.z + 0.057f * c.z + 0.5f;
            o.w = 0.1495f * a.w + 0.2935f * g.w + 0.057f * c.w + 0.5f;
            *(float4*)&sP[OG + r * LG + c4 * 4] = o;
        }
    } else {
        for (int idx = tid; idx < GS * GS; idx += 256) {
            int i = idx / GS, j = idx - i * GS;
            int ry = reflect_i(by0 - 4 + i, IMH);
            int rx = reflect_i(bx0 - 4 + j, IMW);
            int off = ry * IMW + rx;
            sP[OG + i * LG + j] = 0.1495f * p0[off] + 0.2935f * p1[off] + 0.057f * p2[off] + 0.5f;
        }
    }
    __syncthreads();

    // ---- Phase 2: horizontal gaussian -> sH (40 rows x 36 cols) ----
    if (xin) {
        for (int idx = tid; idx < GS * 9; idx += 256) {
            int i = idx / 9, gq = idx - i * 9;
            const float4 A = *(const float4*)&sP[OG + i * LG + 4 * gq];
            const float4 Bv = *(const float4*)&sP[OG + i * LG + 4 * gq + 4];
            float W0 = A.x, W1 = A.y, W2 = A.z, W3 = A.w;
            float W4 = Bv.x, W5 = Bv.y, W6 = Bv.z, W7 = Bv.w;
            float4 o;
            o.x = w0 * (W0 + W4) + w1 * (W1 + W3) + w2 * W2;
            o.y = w0 * (W1 + W5) + w1 * (W2 + W4) + w2 * W3;
            o.z = w0 * (W2 + W6) + w1 * (W3 + W5) + w2 * W4;
            o.w = w0 * (W3 + W7) + w1 * (W4 + W6) + w2 * W5;
            *(float4*)&sP[OH + i * LH + 4 * gq] = o;
        }
    } else {
        for (int idx = tid; idx < GS * 36; idx += 256) {
            int i = idx / 36, j = idx - i * 36;
            int cj = clamp_i(bx0 - 2 + j, IMW) - bx0 + 4;
            const float* gp = &sP[OG + i * LG + cj];
            sP[OH + i * LH + j] = w0 * (gp[-2] + gp[2]) + w1 * (gp[-1] + gp[1]) + w2 * gp[0];
        }
    }
    __syncthreads();

    // ---- Phase 3: vertical gaussian -> sB (rows jy <-> clamp(by0-2+jy), col t=j+4) ----
    for (int idx = tid; idx < 36 * 9; idx += 256) {
        int jy = idx / 9, gq = idx - jy * 9;
        int ci = clamp_i(by0 - 2 + jy, IMH) - by0 + 4;
        int base = OH + ci * LH + 4 * gq;
        const float4 r0 = *(const float4*)&sP[base - 2 * LH];
        const float4 r1 = *(const float4*)&sP[base - LH];
        const float4 r2 = *(const float4*)&sP[base];
        const float4 r3 = *(const float4*)&sP[base + LH];
        const float4 r4 = *(const float4*)&sP[base + 2 * LH];
        float4 o;
        o.x = w0 * (r0.x + r4.x) + w1 * (r1.x + r3.x) + w2 * r2.x;
        o.y = w0 * (r0.y + r4.y) + w1 * (r1.y + r3.y) + w2 * r2.y;
        o.z = w0 * (r0.z + r4.z) + w1 * (r1.z + r3.z) + w2 * r2.z;
        o.w = w0 * (r0.w + r4.w) + w1 * (r1.w + r3.w) + w2 * r2.w;
        *(float4*)&sP[OB + jy * LB + 4 * gq + 4] = o;
    }
    __syncthreads();

    // ---- Phase 4: sobel -> sM (34 rows x slots s=4g..4g+3); stash gx,gy ----
    for (int idx = tid; idx < 34 * 10; idx += 256) {
        int iy = idx / 10, gq = idx - iy * 10;
        // rows: sB slots iy, iy+1, iy+2; cols window floats [4g, 4g+8)
        int baseB = OB + iy * LB + 4 * gq;
        const float4 t0a = *(const float4*)&sP[baseB];
        const float4 t0b = *(const float4*)&sP[baseB + 4];
        const float4 t1a = *(const float4*)&sP[baseB + LB];
        const float4 t1b = *(const float4*)&sP[baseB + LB + 4];
        const float4 t2a = *(const float4*)&sP[baseB + 2 * LB];
        const float4 t2b = *(const float4*)&sP[baseB + 2 * LB + 4];
        float W0[8] = {t0a.x, t0a.y, t0a.z, t0a.w, t0b.x, t0b.y, t0b.z, t0b.w};
        float W1[8] = {t1a.x, t1a.y, t1a.z, t1a.w, t1b.x, t1b.y, t1b.z, t1b.w};
        float W2[8] = {t2a.x, t2a.y, t2a.z, t2a.w, t2b.x, t2b.y, t2b.z, t2b.w};
        float mg[4], gxv[4], gyv[4];
        #pragma unroll
        for (int k = 0; k < 4; ++k) {
            float a00 = W0[k + 1], a01 = W0[k + 2], a02 = W0[k + 3];
            float a10 = W1[k + 1],                  a12 = W1[k + 3];
            float a20 = W2[k + 1], a21 = W2[k + 2], a22 = W2[k + 3];
            float gx = (a02 - a00) + 2.0f * (a12 - a10) + (a22 - a20);
            float gy = (a20 - a00) + 2.0f * (a21 - a01) + (a22 - a02);
            float m = sqrtf(gx * gx + gy * gy + 1e-6f);
            if (!bin) {
                int my = by0 - 1 + iy;
                int cx = bx0 - 4 + 4 * gq + k;
                if (my < 0 || my >= IMH || cx < 0 || cx >= IMW) m = 0.0f;
            }
            mg[k] = m; gxv[k] = gx; gyv[k] = gy;
        }
        *(float4*)&sP[OM + iy * LM + 4 * gq] = make_float4(mg[0], mg[1], mg[2], mg[3]);
        if (gq >= 1 && gq <= 8 && iy >= 1 && iy <= 32) {
            int st = (iy - 1) * LX + 4 * gq - 4;
            *(float4*)&sP[OGX + st] = make_float4(gxv[0], gxv[1], gxv[2], gxv[3]);
            *(float4*)&sP[OGY + st] = make_float4(gyv[0], gyv[1], gyv[2], gyv[3]);
        }
    }
    __syncthreads();

    // ---- Phase 5: octant classification + NMS + store (4 consecutive px/thread) ----
    {
        const int ly  = tid >> 3;
        const int lx0 = (tid & 7) * 4;
        const float4 mag4 = *(const float4*)&sP[OM + (ly + 1) * LM + lx0 + 4];
        const float4 gx4  = *(const float4*)&sP[OGX + ly * LX + lx0];
        const float4 gy4  = *(const float4*)&sP[OGY + ly * LX + lx0];
        const float magv[4] = {mag4.x, mag4.y, mag4.z, mag4.w};
        const float gxv2[4] = {gx4.x, gx4.y, gx4.z, gx4.w};
        const float gyv2[4] = {gy4.x, gy4.y, gy4.z, gy4.w};
        float ov[4];
        #pragma unroll
        for (int k = 0; k < 4; ++k) {
            float gx = gxv2[k], gy = gyv2[k], mag = magv[k];
            float ax = fabsf(gx), ay = fabsf(gy);
            int dy, dx;
            if (ay <= 0.41421356237f * ax)      { dy = 0; dx = 1; }
            else if (ay >= 2.41421356237f * ax) { dy = 1; dx = 0; }
            else                                { dx = 1; dy = (gx * gy > 0.0f) ? -1 : 1; }
            float n1 = sP[OM + (ly + 1 + dy) * LM + (lx0 + k + 4 + dx)];
            float n2 = sP[OM + (ly + 1 - dy) * LM + (lx0 + k + 4 - dx)];
            ov[k] = (mag > n1 && mag > n2) ? mag : 0.0f;
        }
        float4 o4 = make_float4(ov[0], ov[1], ov[2], ov[3]);
        *(float4*)&out[(size_t)b * plane + (size_t)(by0 + ly) * IMW + (bx0 + lx0)] = o4;
    }
}

extern "C" void kernel_launch(void* const* d_in, const int* in_sizes, int n_in,
                              void* d_out, int out_size, void* d_ws, size_t ws_size,
                              hipStream_t stream) {
    const float* data = (const float*)d_in[0];
    float* out = (float*)d_out;
    int B = in_sizes[0] / (3 * IMH * IMW);  // 16
    dim3 grid(IMW / T, IMH / T, B);
    canny_mag_kernel<<<grid, dim3(256, 1, 1), 0, stream>>>(data, out);
}

// Round 4
// 104.041 us; speedup vs baseline: 1.0047x; 1.0047x over previous
//
#include <hip/hip_runtime.h>
#include <math.h>

#define IMH 512
#define IMW 512
#define T   32

// LDS pool (floats). sM aliases dead sH. Pool ~12.8 KB -> 8 blocks/CU (32 waves).
#define LH  36
#define OH  0       // sH: 40 x 36  [0,1440)    col j <-> clamped x = bx0-2+j ; row i <-> raw y = by0-4+i
#define LM  40
#define OM  0       // sM: 34 x 40  [0,1360)    col s <-> x = bx0-4+s (valid s>=3); row iy <-> y = by0-1+iy
#define LB  40
#define OB  1440    // sB: 36 x 40  [1440,2880) col t <-> x = bx0-6+t (valid t>=4); row jy <-> y-slot clamp(by0-2+jy)
#define NPOOL 3200  // padded: phase-C stray window reads + fallback gray staging (40x40 @ OB)

__device__ __forceinline__ int reflect_i(int v, int n) {
    if (v < 0) v = -v;
    if (v >= n) v = 2 * n - 2 - v;
    return v;
}
__device__ __forceinline__ int clamp_i(int v, int n) {
    return v < 0 ? 0 : (v >= n ? n - 1 : v);
}

__global__ __launch_bounds__(256, 8)
void canny_mag_kernel(const float* __restrict__ data, float* __restrict__ out) {
    __shared__ __align__(16) float sP[NPOOL];
    const int bx0 = blockIdx.x * T;
    const int by0 = blockIdx.y * T;
    const int b   = blockIdx.z;
    const int tid = threadIdx.x;
    const bool xin = (bx0 >= 4) && (bx0 + T + 4 <= IMW);
    const bool bin = (bx0 >= 1) && (bx0 + T + 1 <= IMW) &&
                     (by0 >= 1) && (by0 + T + 1 <= IMH);

    const float w0 = 0.05448868f, w1 = 0.24420134f, w2 = 0.40261995f;
    const size_t plane = (size_t)IMH * IMW;
    const float* p0 = data + (size_t)b * 3 * plane;
    const float* p1 = p0 + plane;
    const float* p2 = p1 + plane;

    // ---- Phase A: fused gray + horizontal gaussian -> sH (40 rows x 36 cols) ----
    if (xin) {
        for (int idx = tid; idx < 40 * 9; idx += 256) {
            int i = idx / 9, gq = idx - i * 9;
            int ry = reflect_i(by0 - 4 + i, IMH);
            int off = ry * IMW + (bx0 - 4) + 4 * gq;
            const float4 a0 = *(const float4*)(p0 + off);
            const float4 a1 = *(const float4*)(p0 + off + 4);
            const float4 g0 = *(const float4*)(p1 + off);
            const float4 g1 = *(const float4*)(p1 + off + 4);
            const float4 c0 = *(const float4*)(p2 + off);
            const float4 c1 = *(const float4*)(p2 + off + 4);
            float w[8];
            w[0] = 0.1495f * a0.x + 0.2935f * g0.x + 0.057f * c0.x + 0.5f;
            w[1] = 0.1495f * a0.y + 0.2935f * g0.y + 0.057f * c0.y + 0.5f;
            w[2] = 0.1495f * a0.z + 0.2935f * g0.z + 0.057f * c0.z + 0.5f;
            w[3] = 0.1495f * a0.w + 0.2935f * g0.w + 0.057f * c0.w + 0.5f;
            w[4] = 0.1495f * a1.x + 0.2935f * g1.x + 0.057f * c1.x + 0.5f;
            w[5] = 0.1495f * a1.y + 0.2935f * g1.y + 0.057f * c1.y + 0.5f;
            w[6] = 0.1495f * a1.z + 0.2935f * g1.z + 0.057f * c1.z + 0.5f;
            w[7] = 0.1495f * a1.w + 0.2935f * g1.w + 0.057f * c1.w + 0.5f;
            float4 o;
            o.x = w0 * (w[0] + w[4]) + w1 * (w[1] + w[3]) + w2 * w[2];
            o.y = w0 * (w[1] + w[5]) + w1 * (w[2] + w[4]) + w2 * w[3];
            o.z = w0 * (w[2] + w[6]) + w1 * (w[3] + w[5]) + w2 * w[4];
            o.w = w0 * (w[3] + w[7]) + w1 * (w[4] + w[6]) + w2 * w[5];
            *(float4*)&sP[OH + i * LH + 4 * gq] = o;
        }
    } else {
        // stage reflected gray (40x40, stride 40) into the (currently dead) sB region
        for (int idx = tid; idx < 40 * 40; idx += 256) {
            int i = idx / 40, j = idx - i * 40;
            int ry = reflect_i(by0 - 4 + i, IMH);
            int rx = reflect_i(bx0 - 4 + j, IMW);
            int off = ry * IMW + rx;
            sP[OB + i * 40 + j] = 0.1495f * p0[off] + 0.2935f * p1[off] + 0.057f * p2[off] + 0.5f;
        }
        __syncthreads();
        for (int idx = tid; idx < 40 * 36; idx += 256) {
            int i = idx / 36, j = idx - i * 36;
            int cj = clamp_i(bx0 - 2 + j, IMW) - bx0 + 4;  // slot in staged gray
            const float* gp = &sP[OB + i * 40 + cj];
            sP[OH + i * LH + j] = w0 * (gp[-2] + gp[2]) + w1 * (gp[-1] + gp[1]) + w2 * gp[0];
        }
    }
    __syncthreads();

    // ---- Phase B: vertical gaussian -> sB (36 rows x cols t=4..39) ----
    for (int idx = tid; idx < 36 * 9; idx += 256) {
        int jy = idx / 9, gq = idx - jy * 9;
        int ci = clamp_i(by0 - 2 + jy, IMH) - by0 + 4;
        int base = OH + ci * LH + 4 * gq;
        const float4 r0 = *(const float4*)&sP[base - 2 * LH];
        const float4 r1 = *(const float4*)&sP[base - LH];
        const float4 r2 = *(const float4*)&sP[base];
        const float4 r3 = *(const float4*)&sP[base + LH];
        const float4 r4 = *(const float4*)&sP[base + 2 * LH];
        float4 o;
        o.x = w0 * (r0.x + r4.x) + w1 * (r1.x + r3.x) + w2 * r2.x;
        o.y = w0 * (r0.y + r4.y) + w1 * (r1.y + r3.y) + w2 * r2.y;
        o.z = w0 * (r0.z + r4.z) + w1 * (r1.z + r3.z) + w2 * r2.z;
        o.w = w0 * (r0.w + r4.w) + w1 * (r1.w + r3.w) + w2 * r2.w;
        *(float4*)&sP[OB + jy * LB + 4 * gq + 4] = o;
    }
    __syncthreads();

    // ---- Phase C: sobel -> magnitude into sM (writes all 40 slots; s<3, s>36 are don't-care) ----
    for (int idx = tid; idx < 34 * 10; idx += 256) {
        int iy = idx / 10, gq = idx - iy * 10;
        int baseB = OB + iy * LB + 4 * gq;
        const float4 t0a = *(const float4*)&sP[baseB];
        const float4 t0b = *(const float4*)&sP[baseB + 4];
        const float4 t1a = *(const float4*)&sP[baseB + LB];
        const float4 t1b = *(const float4*)&sP[baseB + LB + 4];
        const float4 t2a = *(const float4*)&sP[baseB + 2 * LB];
        const float4 t2b = *(const float4*)&sP[baseB + 2 * LB + 4];
        float W0[8] = {t0a.x, t0a.y, t0a.z, t0a.w, t0b.x, t0b.y, t0b.z, t0b.w};
        float W1[8] = {t1a.x, t1a.y, t1a.z, t1a.w, t1b.x, t1b.y, t1b.z, t1b.w};
        float W2[8] = {t2a.x, t2a.y, t2a.z, t2a.w, t2b.x, t2b.y, t2b.z, t2b.w};
        float mg[4];
        #pragma unroll
        for (int k = 0; k < 4; ++k) {
            float a00 = W0[k + 1], a01 = W0[k + 2], a02 = W0[k + 3];
            float a10 = W1[k + 1],                  a12 = W1[k + 3];
            float a20 = W2[k + 1], a21 = W2[k + 2], a22 = W2[k + 3];
            float gx = (a02 - a00) + 2.0f * (a12 - a10) + (a22 - a20);
            float gy = (a20 - a00) + 2.0f * (a21 - a01) + (a22 - a02);
            float m = sqrtf(gx * gx + gy * gy + 1e-6f);
            if (!bin) {
                int my = by0 - 1 + iy;
                int cx = bx0 - 4 + 4 * gq + k;
                if (my < 0 || my >= IMH || cx < 0 || cx >= IMW) m = 0.0f;
            }
            mg[k] = m;
        }
        *(float4*)&sP[OM + iy * LM + 4 * gq] = make_float4(mg[0], mg[1], mg[2], mg[3]);
    }
    __syncthreads();

    // ---- Phase D: recompute sobel from sB, octant classify, NMS, store (4 px/thread) ----
    {
        const int ly  = tid >> 3;         // 0..31
        const int lx0 = (tid & 7) * 4;    // 0,4,..,28
        const float4 m4 = *(const float4*)&sP[OM + (ly + 1) * LM + lx0 + 4];
        const int bB = OB + (ly + 1) * LB + lx0 + 4;
        const float4 u0a = *(const float4*)&sP[bB];
        const float4 u0b = *(const float4*)&sP[bB + 4];
        const float4 u1a = *(const float4*)&sP[bB + LB];
        const float4 u1b = *(const float4*)&sP[bB + LB + 4];
        const float4 u2a = *(const float4*)&sP[bB + 2 * LB];
        const float4 u2b = *(const float4*)&sP[bB + 2 * LB + 4];
        float U0[8] = {u0a.x, u0a.y, u0a.z, u0a.w, u0b.x, u0b.y, u0b.z, u0b.w};
        float U1[8] = {u1a.x, u1a.y, u1a.z, u1a.w, u1b.x, u1b.y, u1b.z, u1b.w};
        float U2[8] = {u2a.x, u2a.y, u2a.z, u2a.w, u2b.x, u2b.y, u2b.z, u2b.w};
        const float magv[4] = {m4.x, m4.y, m4.z, m4.w};
        float ov[4];
        #pragma unroll
        for (int k = 0; k < 4; ++k) {
            float a00 = U0[k + 1], a01 = U0[k + 2], a02 = U0[k + 3];
            float a10 = U1[k + 1],                  a12 = U1[k + 3];
            float a20 = U2[k + 1], a21 = U2[k + 2], a22 = U2[k + 3];
            float gx = (a02 - a00) + 2.0f * (a12 - a10) + (a22 - a20);
            float gy = (a20 - a00) + 2.0f * (a21 - a01) + (a22 - a02);
            float ax = fabsf(gx), ay = fabsf(gy);
            int dy, dx;
            if (ay <= 0.41421356237f * ax)      { dy = 0; dx = 1; }
            else if (ay >= 2.41421356237f * ax) { dy = 1; dx = 0; }
            else                                { dx = 1; dy = (gx * gy > 0.0f) ? -1 : 1; }
            float n1 = sP[OM + (ly + 1 + dy) * LM + (lx0 + k + 4 + dx)];
            float n2 = sP[OM + (ly + 1 - dy) * LM + (lx0 + k + 4 - dx)];
            float mag = magv[k];
            ov[k] = (mag > n1 && mag > n2) ? mag : 0.0f;
        }
        float4 o4 = make_float4(ov[0], ov[1], ov[2], ov[3]);
        *(float4*)&out[(size_t)b * plane + (size_t)(by0 + ly) * IMW + (bx0 + lx0)] = o4;
    }
}

extern "C" void kernel_launch(void* const* d_in, const int* in_sizes, int n_in,
                              void* d_out, int out_size, void* d_ws, size_t ws_size,
                              hipStream_t stream) {
    const float* data = (const float*)d_in[0];
    float* out = (float*)d_out;
    int B = in_sizes[0] / (3 * IMH * IMW);  // 16
    dim3 grid(IMW / T, IMH / T, B);
    canny_mag_kernel<<<grid, dim3(256, 1, 1), 0, stream>>>(data, out);
}

// Round 5
// 93.002 us; speedup vs baseline: 1.1240x; 1.1187x over previous
//
#include <hip/hip_runtime.h>
#include <math.h>

#define IMH 512
#define IMW 512
#define RB    32    // output rows per wave-band
#define NBAND 16    // IMH / RB
#define NWC   10    // wave-columns: out width 56 each, c0 = 56*wc - 4
#define OUTW  56

__device__ __forceinline__ int reflect_i(int v, int n) {
    if (v < 0) v = -v;
    if (v >= n) v = 2 * n - 2 - v;
    return v;
}

// One wave = one 64-col x RB-row band. lane = column (cx = c0+lane).
// Pipeline per row-step yL:  gray(yL) -> hblur(yL) -> vblur row yL-2 ->
// sobel row yL-3 -> mag -> NMS+store row yL-4.  No LDS, no barriers.
__global__ __launch_bounds__(256)
void canny_stream(const float* __restrict__ data, float* __restrict__ out) {
    const int lane = threadIdx.x & 63;
    const int wid  = (blockIdx.x << 2) + (threadIdx.x >> 6);
    const int wc   = wid % NWC;
    const int t2   = wid / NWC;
    const int band = t2 & (NBAND - 1);
    const int bat  = t2 >> 4;

    const int c0 = OUTW * wc - 4;
    const int cx = c0 + lane;
    const int y0 = band * RB;

    const size_t plane = (size_t)(IMH * IMW);
    const float* p0 = data + (size_t)bat * 3 * plane;
    const float* p1 = p0 + plane;
    const float* p2 = p1 + plane;
    float* outp = out + (size_t)bat * plane;

    const int rx  = reflect_i(cx, IMW);          // reflect-pad col (loads)
    const int lm2 = lane - 2, lm1 = lane - 1, lp1 = lane + 1, lp2 = lane + 2;
    // sobel col neighbors use EDGE-clamped blurred: lane holding clamp(cx+-1)
    const int ixm = (cx - 1 < 0 ? 0 : (cx - 1 >= IMW ? IMW - 1 : cx - 1)) - c0;
    const int ixp = (cx + 1 < 0 ? 0 : (cx + 1 >= IMW ? IMW - 1 : cx + 1)) - c0;

    const float w0 = 0.05448868f, w1 = 0.24420134f, w2 = 0.40261995f;

    // rolling rings
    float h0 = 0, h1 = 0, h2 = 0, h3 = 0;                 // hblur rows yL-4..yL-1
    float b_1 = 0, b_0 = 0, bl_1 = 0, bl_0 = 0, br_1 = 0, br_0 = 0;  // blurred u-1,u
    float m_1 = 0, m_0 = 0, ml_1 = 0, ml_0 = 0, mr_1 = 0, mr_0 = 0;  // mag s-1,s
    float gxp = 0, gyp = 0;                                // sobel at row s

    auto process = [&](int yL, float gray) {
        // horizontal blur (row yL); lanes hold reflect-padded gray -> plain shifts
        float gm2 = __shfl(gray, lm2);
        float gm1 = __shfl(gray, lm1);
        float gp1 = __shfl(gray, lp1);
        float gp2 = __shfl(gray, lp2);
        float hnew = w0 * (gm2 + gp2) + w1 * (gm1 + gp1) + w2 * gray;
        // vertical blur -> row v = yL-2 (rows reflect-padded at load)
        float bnew = w0 * (h0 + hnew) + w1 * (h1 + h3) + w2 * h2;
        float blnew = __shfl(bnew, ixm);   // blurred at clamp(cx-1)
        float brnew = __shfl(bnew, ixp);   // blurred at clamp(cx+1)
        // sobel -> row u = yL-3, rows edge-clamped
        int u = yL - 3;
        float ta  = (u == 0) ? b_0 : b_1;          // row u-1
        float tla = (u == 0) ? bl_0 : bl_1;
        float tra = (u == 0) ? br_0 : br_1;
        float tb  = (u == IMH - 1) ? b_0 : bnew;   // row u+1
        float tlb = (u == IMH - 1) ? bl_0 : blnew;
        float trb = (u == IMH - 1) ? br_0 : brnew;
        float gx = (tra - tla) + 2.0f * (br_0 - bl_0) + (trb - tlb);
        float gy = (tlb - tla) + 2.0f * (tb - ta) + (trb - tra);
        float mnew = sqrtf(gx * gx + gy * gy + 1e-6f);
        if ((unsigned)cx >= (unsigned)IMW) mnew = 0.0f;   // NMS zero-pad cols
        float mlnew = __shfl(mnew, lm1);
        float mrnew = __shfl(mnew, lp1);
        // NMS -> row s = yL-4 (gxp/gyp = sobel at row s, from prev step)
        int s = yL - 4;
        if (s >= y0) {
            float pm  = (s == 0) ? 0.0f : m_1;     // row s-1 (zero-pad rows)
            float pml = (s == 0) ? 0.0f : ml_1;
            float pmr = (s == 0) ? 0.0f : mr_1;
            float nm  = (s == IMH - 1) ? 0.0f : mnew;   // row s+1
            float nml = (s == IMH - 1) ? 0.0f : mlnew;
            float nmr = (s == IMH - 1) ? 0.0f : mrnew;
            float ax = fabsf(gxp), ay = fabsf(gyp);
            bool ew = (ay <= 0.41421356237f * ax);
            bool ns = (ay >= 2.41421356237f * ax);
            bool d1 = (gxp * gyp > 0.0f);          // dy=-1,dx=+1 axis
            float n1 = ew ? mr_0 : (ns ? nm : (d1 ? pmr : nmr));
            float n2 = ew ? ml_0 : (ns ? pm : (d1 ? nml : pml));
            float mag = m_0;
            float o = (mag > n1 && mag > n2) ? mag : 0.0f;
            if (lane >= 4 && lane < 60 && (unsigned)cx < (unsigned)IMW)
                outp[(size_t)s * IMW + cx] = o;
        }
        // rotate rings
        h0 = h1; h1 = h2; h2 = h3; h3 = hnew;
        b_1 = b_0;  b_0 = bnew;
        bl_1 = bl_0; bl_0 = blnew;
        br_1 = br_0; br_0 = brnew;
        m_1 = m_0;  m_0 = mnew;
        ml_1 = ml_0; ml_0 = mlnew;
        mr_1 = mr_0; mr_0 = mrnew;
        gxp = gx; gyp = gy;
    };

    // depth-2 software prefetch (A/B double buffer), rows yL = y0-4 .. y0+RB+3
    int ya = reflect_i(y0 - 4, IMH) * IMW;
    float rA = p0[ya + rx], gA = p1[ya + rx], cA = p2[ya + rx];
    int yb = reflect_i(y0 - 3, IMH) * IMW;
    float rB = p0[yb + rx], gB = p1[yb + rx], cB = p2[yb + rx];

    #pragma unroll 2
    for (int tt = 0; tt < (RB + 8) / 2; ++tt) {
        int yL = y0 - 4 + 2 * tt;
        float grayA = 0.1495f * rA + 0.2935f * gA + 0.057f * cA + 0.5f;
        int yr = reflect_i(yL + 2, IMH) * IMW;
        rA = p0[yr + rx]; gA = p1[yr + rx]; cA = p2[yr + rx];
        process(yL, grayA);
        float grayB = 0.1495f * rB + 0.2935f * gB + 0.057f * cB + 0.5f;
        int yr2 = reflect_i(yL + 3, IMH) * IMW;
        rB = p0[yr2 + rx]; gB = p1[yr2 + rx]; cB = p2[yr2 + rx];
        process(yL + 1, grayB);
    }
}

extern "C" void kernel_launch(void* const* d_in, const int* in_sizes, int n_in,
                              void* d_out, int out_size, void* d_ws, size_t ws_size,
                              hipStream_t stream) {
    const float* data = (const float*)d_in[0];
    float* out = (float*)d_out;
    int B = in_sizes[0] / (3 * IMH * IMW);   // 16
    // waves = B * NBAND * NWC; 4 waves per 256-thread block
    int blocks = (B * NBAND * NWC) / 4;
    canny_stream<<<blocks, dim3(256, 1, 1), 0, stream>>>(data, out);
}